// Round 1
// baseline (548.101 us; speedup 1.0000x reference)
//
#include <hip/hip_runtime.h>

#define D   256
#define WR  129          // D/2 + 1
#define B   64
static constexpr long PL = (long)D * D * WR;   // one output plane: 8,454,144 floats
#define SQRT3 1.7320509f

// ===========================================================================
// Radix-2 Stockham FFT, 256-point, one wave (64 lanes) per transform,
// 4 transforms per 256-thread block, LDS ping-pong X<->Y. After 8 stages the
// natural-order result is back in X. Twiddles: one 128-entry table tw256[j] =
// exp(-2*pi*i*j/256) serves every stage via index pm = u & ~(s-1).
// ===========================================================================

// ---------------------------------------------------------------------------
// Kernel 1: row rfft. Packs rows (2rp, 2rp+1) as one complex signal, FFTs,
// untangles to 129 bins, writes transposed F1T[b][k][y] (float2), with the
// (k, y-pair) pair stored as one float4 (16B contiguous).
// Grid: B*D/2/4 = 2048 blocks.
// ---------------------------------------------------------------------------
__global__ void __launch_bounds__(256) row_fft_kernel(const float* __restrict__ imgs,
                                                      float2* __restrict__ F1T) {
    __shared__ float2 Xs[4][D];
    __shared__ float2 Ys[4][D];
    __shared__ float2 tws[128];

    const int t = threadIdx.x;
    const int f = t >> 6;          // transform id within block
    const int r = t & 63;          // lane within transform
    const int blk = blockIdx.x;
    const int b   = blk >> 5;              // 32 blocks per image
    const int rp  = ((blk & 31) << 2) + f; // row pair: rows 2rp, 2rp+1

    if (t < 128) {
        float s, c;
        sincospif(-(float)t * (1.0f / 128.0f), &s, &c);
        tws[t] = make_float2(c, s);
    }

    // load: z[n] = row0[n] + i*row1[n], conflict-free stride-64 pattern
    {
        const float* r0 = imgs + ((size_t)(b * D + 2 * rp)) * D;
        const float* r1 = r0 + D;
        #pragma unroll
        for (int j = 0; j < 4; ++j) {
            const int n = r + 64 * j;
            Xs[f][n] = make_float2(r0[n], r1[n]);
        }
    }
    __syncthreads();

    float2* Xf = Xs[f];
    float2* Yf = Ys[f];
    #pragma unroll
    for (int st = 0; st < 8; ++st) {
        float2* src = (st & 1) ? Yf : Xf;
        float2* dst = (st & 1) ? Xf : Yf;
        const int sB = 1 << st;
        #pragma unroll
        for (int hh = 0; hh < 2; ++hh) {
            const int u  = r + 64 * hh;
            const int pm = u & ~(sB - 1);
            const float2 a  = src[u];
            const float2 bv = src[u + 128];
            const float2 w  = tws[pm];
            const float dx = a.x - bv.x, dy = a.y - bv.y;
            const int o = u + pm;
            dst[o]      = make_float2(a.x + bv.x, a.y + bv.y);
            dst[o + sB] = make_float2(dx * w.x - dy * w.y, dx * w.y + dy * w.x);
        }
        __syncthreads();
    }
    // result in Xf, natural order

    // untangle real pair + transposed store: F1T[(b*129+k)*256 + {2rp,2rp+1}]
    for (int k = r; k <= 128; k += 64) {
        const float2 zk = Xf[k];
        const float2 zm = Xf[(256 - k) & 255];
        // Fe = 0.5(zk + conj(zm)); Fo = -0.5i(zk - conj(zm))
        const float4 o4 = make_float4(0.5f * (zk.x + zm.x), 0.5f * (zk.y - zm.y),
                                      0.5f * (zk.y + zm.y), -0.5f * (zk.x - zm.x));
        *(float4*)&F1T[((size_t)(b * WR + k)) * D + 2 * rp] = o4;
    }
}

// ---------------------------------------------------------------------------
// Kernel 2: column FFT over y for each (b,x), + fftshift + phase + CTF.
// Reads F1T[b][x][y] (contiguous), writes F4[b][h][x] (gather layout).
// Grid: B*WR/4 = 2064 blocks.
// ---------------------------------------------------------------------------
__global__ void __launch_bounds__(256) col_fft_kernel(const float2* __restrict__ F1T,
                                                      const float* __restrict__ ctf,
                                                      const float* __restrict__ hwShiftAngs,
                                                      float4* __restrict__ F4) {
    __shared__ float2 Xs[4][D];
    __shared__ float2 Ys[4][D];
    __shared__ float2 tws[128];

    const int t = threadIdx.x;
    const int f = t >> 6;
    const int r = t & 63;
    const int c = blockIdx.x * 4 + f;   // b*129 + x
    const int b = c / WR;
    const int x = c - b * WR;

    if (t < 128) {
        float s, cc;
        sincospif(-(float)t * (1.0f / 128.0f), &s, &cc);
        tws[t] = make_float2(cc, s);
    }

    {
        const float2* src = F1T + (size_t)c * D;
        #pragma unroll
        for (int j = 0; j < 4; ++j) {
            const int n = r + 64 * j;
            Xs[f][n] = src[n];
        }
    }
    __syncthreads();

    float2* Xf = Xs[f];
    float2* Yf = Ys[f];
    #pragma unroll
    for (int st = 0; st < 8; ++st) {
        float2* src = (st & 1) ? Yf : Xf;
        float2* dst = (st & 1) ? Xf : Yf;
        const int sB = 1 << st;
        #pragma unroll
        for (int hh = 0; hh < 2; ++hh) {
            const int u  = r + 64 * hh;
            const int pm = u & ~(sB - 1);
            const float2 a  = src[u];
            const float2 bv = src[u + 128];
            const float2 w  = tws[pm];
            const float dx = a.x - bv.x, dy = a.y - bv.y;
            const int o = u + pm;
            dst[o]      = make_float2(a.x + bv.x, a.y + bv.y);
            dst[o + sB] = make_float2(dx * w.x - dy * w.y, dx * w.y + dy * w.x);
        }
        __syncthreads();
    }

    const float sy = hwShiftAngs[b * 2 + 0];
    const float sx = hwShiftAngs[b * 2 + 1];

    #pragma unroll
    for (int j = 0; j < 4; ++j) {
        const int tt = r + 64 * j;                 // frequency index (pre-shift)
        const int h  = (tt + D / 2) & (D - 1);     // fftshifted row
        const float ky = (float)(h - D / 2);
        const float2 z = Xf[tt];
        const float ph = -2.0f * (ky * sy + (float)x * sx) * (1.0f / (float)D);
        float ps, pc;
        sincospif(ph, &ps, &pc);
        const float ore = z.x * pc - z.y * ps;
        const float oim = z.x * ps + z.y * pc;
        const size_t o = (size_t)(b * D + h) * WR + x;
        const float cf = ctf[o];
        F4[o] = make_float4(cf * ore, cf * oim, cf * cf, 0.f);
    }
}

// ---------------------------------------------------------------------------
// Kernel 3: tiled GATHER.
// Round-1 changes vs the 546.7us baseline:
//  (a) wave footprint 4x4x4 (block still covers the same 16x4x4 tile; the 4
//      waves tile x in 4-wide chunks). Wave qz-spread drops ~9 -> ~4.5 voxels,
//      so the in-slab lane fraction during the inner loops rises ~28% -> ~43%.
//  (b) exact per-particle L1-norm radii (<= sqrt3) for the slab test and both
//      bbox dims, stored in the previously-unused aR slots 3/7/11. Strictly a
//      superset of all w>0 taps: |Delta . u| >= ||u||_1 => some |Delta_i| >= 1
//      => that tap's weight is 0.
//  (c) per-ky hoisted fold constants: dz/dy become single fmas per tap. The
//      fold-membership rx expression stays bit-identical to the scatter ref.
// ---------------------------------------------------------------------------
#define TX 16
#define TY 4
#define TZ 4

__global__ void __launch_bounds__(256) gather_kernel(const float4* __restrict__ F4,
                                                     const float* __restrict__ rotMats,
                                                     float* __restrict__ out) {
    __shared__ float aR[B][12];
    __shared__ int   aBase[B];
    __shared__ int   na_s;

    const int t  = threadIdx.x;
    const int x0 = blockIdx.x * TX;
    const int y0 = blockIdx.y * TY;
    const int z0 = blockIdx.z * TZ;

    const float cx = (float)x0 + 7.5f;
    const float cy = (float)y0 + 1.5f - 128.f;
    const float cz = (float)z0 + 1.5f - 128.f;

    if (t < 64) {                       // wave 0: particle culling + compaction
        const float* R = rotMats + t * 9;
        const float R0 = R[0], R1 = R[1], R2 = R[2];
        const float R3 = R[3], R4 = R[4], R5 = R[5];
        const float R6 = R[6], R7 = R[7], R8 = R[8];
        const float qzc = R0 * cz + R3 * cy + R6 * cx;
        const float qyc = R1 * cz + R4 * cy + R7 * cx;
        const float qxc = R2 * cz + R5 * cy + R8 * cx;
        const float radz = fabsf(R0) + fabsf(R3) + fabsf(R6);   // ||col_z||_1
        const float rady = fabsf(R1) + fabsf(R4) + fabsf(R7);   // ||col_y||_1
        const float radx = fabsf(R2) + fabsf(R5) + fabsf(R8);   // ||col_x||_1
        const float mz = radz  + 1.5f * fabsf(R0) + 1.5f * fabsf(R3) + 7.5f * fabsf(R6);
        const float my = 130.f + 1.5f * fabsf(R1) + 1.5f * fabsf(R4) + 7.5f * fabsf(R7);
        const float mx = 130.f + 1.5f * fabsf(R2) + 1.5f * fabsf(R5) + 7.5f * fabsf(R8);
        const bool pass = (fabsf(qzc) < mz) & (fabsf(qyc) < my) & (fabsf(qxc) < mx);
        const unsigned long long m = __ballot(pass);
        if (t == 0) na_s = (int)__popcll(m);
        if (pass) {
            const int a = (int)__popcll(m & ((1ull << t) - 1ull));
            aR[a][0] = R0; aR[a][1] = R3; aR[a][2]  = R6;  aR[a][3]  = radz; // col z
            aR[a][4] = R1; aR[a][5] = R4; aR[a][6]  = R7;  aR[a][7]  = rady; // col y
            aR[a][8] = R2; aR[a][9] = R5; aR[a][10] = R8;  aR[a][11] = radx; // col x
            aBase[a] = t * D * WR;
        }
    }
    __syncthreads();

    // 4x4x4 subcube per wave; waves tile x in 4-wide chunks
    const int x = x0 + ((t >> 6) << 2) + (t & 3);
    const int y = y0 + ((t >> 2) & 3);
    const int z = z0 + ((t >> 4) & 3);
    if (x >= WR) return;               // only in the last x-tile; no barriers below

    const float vx = (float)x;
    const float vy = (float)(y - 128);
    const float vz = (float)(z - 128);

    float nre = 0.f, nim = 0.f, wv = 0.f, cv = 0.f;
    const int na = na_s;

    for (int a = 0; a < na; ++a) {
        const float* Rb = aR[a];
        const float qz = Rb[0] * vz + Rb[1] * vy + Rb[2] * vx;
        const float radz = Rb[3];
        if (fabsf(qz) >= radz) continue;
        const float R1 = Rb[4], R4 = Rb[5], R7 = Rb[6];
        const float rady = Rb[7];
        const float R2 = Rb[8], R5 = Rb[9], R8 = Rb[10];
        const float radx = Rb[11];
        const float qy = R1 * vz + R4 * vy + R7 * vx;
        const float qx = R2 * vz + R5 * vy + R8 * vx;
        const int base = aBase[a];

        #pragma unroll
        for (int fi = 0; fi < 2; ++fi) {
            const float fs = fi ? -1.f : 1.f;
            const float ty = fi ? -qy : qy;
            const float tx = fi ? -qx : qx;
            int ky0 = (int)ceilf(ty - rady);  ky0 = max(ky0, -D / 2);
            int ky1 = (int)floorf(ty + rady); ky1 = min(ky1, D / 2 - 1);
            int kx0 = (int)ceilf(tx - radx);  kx0 = max(kx0, 0);
            int kx1 = (int)floorf(tx + radx); kx1 = min(kx1, WR - 1);
            if (ky0 > ky1 || kx0 > kx1) continue;

            for (int ky = ky0; ky <= ky1; ++ky) {
                const float kyf = (float)ky;
                const float sx = R7 * kyf;                    // for rx (exact scatter expr)
                const float bz = fmaf(fs * R1, kyf, -vz);     // fs*R1*ky - vz
                const float by = fmaf(fs * R4, kyf, -vy);
                const int rowb = base + (ky + D / 2) * WR;
                for (int kx = kx0; kx <= kx1; ++kx) {
                    const float kxf = (float)kx;
                    const float rx = fmaf(R8, kxf, sx);       // matches scatter expr
                    if ((rx < 0.f) != (fi == 1)) continue;    // fold membership
                    const float dz_ = fmaf(fs * R2, kxf, bz);
                    const float az  = fabsf(dz_); if (az >= 1.f) continue;
                    const float dy_ = fmaf(fs * R5, kxf, by);
                    const float ay  = fabsf(dy_); if (ay >= 1.f) continue;
                    const float dx_ = fs * rx - vx;
                    const float ax  = fabsf(dx_); if (ax >= 1.f) continue;
                    const float w = (1.f - az) * (1.f - ay) * (1.f - ax);
                    const float4 v = F4[rowb + kx];
                    nre = fmaf(w, v.x, nre);
                    nim = fmaf(w, fi ? -v.y : v.y, nim);
                    wv += w;
                    cv  = fmaf(w, v.z, cv);
                }
            }
        }
    }

    const long idx = (long)z * (D * WR) + (long)y * WR + x;
    out[idx]          = nre;
    out[PL + idx]     = nim;
    out[2 * PL + idx] = wv;
    out[3 * PL + idx] = cv;
}

// ---------------------------------------------------------------------------
extern "C" void kernel_launch(void* const* d_in, const int* in_sizes, int n_in,
                              void* d_out, int out_size, void* d_ws, size_t ws_size,
                              hipStream_t stream) {
    const float* imgs    = (const float*)d_in[0];   // [B, D, D]
    const float* ctf     = (const float*)d_in[1];   // [B, D, WR]
    const float* rotMats = (const float*)d_in[2];   // [B, 3, 3]
    const float* hw      = (const float*)d_in[3];   // [B, 2]
    float* out = (float*)d_out;                     // [4, D, D, WR]

    float2* F1T = (float2*)d_ws;                                   // [B,WR,D] complex (16.9 MB)
    float4* F4  = (float4*)((char*)d_ws + (size_t)B * D * WR * 8); // [B,D,WR] float4 (33.8 MB)

    row_fft_kernel<<<B * D / 2 / 4, 256, 0, stream>>>(imgs, F1T);
    col_fft_kernel<<<B * WR / 4, 256, 0, stream>>>(F1T, ctf, hw, F4);

    dim3 grid((WR + TX - 1) / TX, D / TY, D / TZ);   // 9 x 64 x 64
    gather_kernel<<<grid, 256, 0, stream>>>(F4, rotMats, out);
}

// Round 2
// 479.486 us; speedup vs baseline: 1.1431x; 1.1431x over previous
//
#include <hip/hip_runtime.h>

#define D   256
#define WR  129          // D/2 + 1
#define B   64
static constexpr long PL = (long)D * D * WR;   // one output plane: 8,454,144 floats
#define SQRT3 1.7320509f

// ===========================================================================
// Radix-2 Stockham FFT, 256-point, one wave (64 lanes) per transform,
// 4 transforms per 256-thread block, LDS ping-pong X<->Y. After 8 stages the
// natural-order result is back in X. Twiddles: one 128-entry table tw256[j] =
// exp(-2*pi*i*j/256) serves every stage via index pm = u & ~(s-1).
// ===========================================================================

// ---------------------------------------------------------------------------
// Kernel 1: row rfft. Packs rows (2rp, 2rp+1) as one complex signal, FFTs,
// untangles to 129 bins, writes transposed F1T[b][k][y] (float2), with the
// (k, y-pair) pair stored as one float4 (16B contiguous).
// Grid: B*D/2/4 = 2048 blocks.
// ---------------------------------------------------------------------------
__global__ void __launch_bounds__(256) row_fft_kernel(const float* __restrict__ imgs,
                                                      float2* __restrict__ F1T) {
    __shared__ float2 Xs[4][D];
    __shared__ float2 Ys[4][D];
    __shared__ float2 tws[128];

    const int t = threadIdx.x;
    const int f = t >> 6;          // transform id within block
    const int r = t & 63;          // lane within transform
    const int blk = blockIdx.x;
    const int b   = blk >> 5;              // 32 blocks per image
    const int rp  = ((blk & 31) << 2) + f; // row pair: rows 2rp, 2rp+1

    if (t < 128) {
        float s, c;
        sincospif(-(float)t * (1.0f / 128.0f), &s, &c);
        tws[t] = make_float2(c, s);
    }

    // load: z[n] = row0[n] + i*row1[n], conflict-free stride-64 pattern
    {
        const float* r0 = imgs + ((size_t)(b * D + 2 * rp)) * D;
        const float* r1 = r0 + D;
        #pragma unroll
        for (int j = 0; j < 4; ++j) {
            const int n = r + 64 * j;
            Xs[f][n] = make_float2(r0[n], r1[n]);
        }
    }
    __syncthreads();

    float2* Xf = Xs[f];
    float2* Yf = Ys[f];
    #pragma unroll
    for (int st = 0; st < 8; ++st) {
        float2* src = (st & 1) ? Yf : Xf;
        float2* dst = (st & 1) ? Xf : Yf;
        const int sB = 1 << st;
        #pragma unroll
        for (int hh = 0; hh < 2; ++hh) {
            const int u  = r + 64 * hh;
            const int pm = u & ~(sB - 1);
            const float2 a  = src[u];
            const float2 bv = src[u + 128];
            const float2 w  = tws[pm];
            const float dx = a.x - bv.x, dy = a.y - bv.y;
            const int o = u + pm;
            dst[o]      = make_float2(a.x + bv.x, a.y + bv.y);
            dst[o + sB] = make_float2(dx * w.x - dy * w.y, dx * w.y + dy * w.x);
        }
        __syncthreads();
    }
    // result in Xf, natural order

    // untangle real pair + transposed store: F1T[(b*129+k)*256 + {2rp,2rp+1}]
    for (int k = r; k <= 128; k += 64) {
        const float2 zk = Xf[k];
        const float2 zm = Xf[(256 - k) & 255];
        // Fe = 0.5(zk + conj(zm)); Fo = -0.5i(zk - conj(zm))
        const float4 o4 = make_float4(0.5f * (zk.x + zm.x), 0.5f * (zk.y - zm.y),
                                      0.5f * (zk.y + zm.y), -0.5f * (zk.x - zm.x));
        *(float4*)&F1T[((size_t)(b * WR + k)) * D + 2 * rp] = o4;
    }
}

// ---------------------------------------------------------------------------
// Kernel 2: column FFT over y for each (b,x), + fftshift + phase + CTF.
// Reads F1T[b][x][y] (contiguous), writes F4[b][h][x] (gather layout).
// Grid: B*WR/4 = 2064 blocks.
// ---------------------------------------------------------------------------
__global__ void __launch_bounds__(256) col_fft_kernel(const float2* __restrict__ F1T,
                                                      const float* __restrict__ ctf,
                                                      const float* __restrict__ hwShiftAngs,
                                                      float4* __restrict__ F4) {
    __shared__ float2 Xs[4][D];
    __shared__ float2 Ys[4][D];
    __shared__ float2 tws[128];

    const int t = threadIdx.x;
    const int f = t >> 6;
    const int r = t & 63;
    const int c = blockIdx.x * 4 + f;   // b*129 + x
    const int b = c / WR;
    const int x = c - b * WR;

    if (t < 128) {
        float s, cc;
        sincospif(-(float)t * (1.0f / 128.0f), &s, &cc);
        tws[t] = make_float2(cc, s);
    }

    {
        const float2* src = F1T + (size_t)c * D;
        #pragma unroll
        for (int j = 0; j < 4; ++j) {
            const int n = r + 64 * j;
            Xs[f][n] = src[n];
        }
    }
    __syncthreads();

    float2* Xf = Xs[f];
    float2* Yf = Ys[f];
    #pragma unroll
    for (int st = 0; st < 8; ++st) {
        float2* src = (st & 1) ? Yf : Xf;
        float2* dst = (st & 1) ? Xf : Yf;
        const int sB = 1 << st;
        #pragma unroll
        for (int hh = 0; hh < 2; ++hh) {
            const int u  = r + 64 * hh;
            const int pm = u & ~(sB - 1);
            const float2 a  = src[u];
            const float2 bv = src[u + 128];
            const float2 w  = tws[pm];
            const float dx = a.x - bv.x, dy = a.y - bv.y;
            const int o = u + pm;
            dst[o]      = make_float2(a.x + bv.x, a.y + bv.y);
            dst[o + sB] = make_float2(dx * w.x - dy * w.y, dx * w.y + dy * w.x);
        }
        __syncthreads();
    }

    const float sy = hwShiftAngs[b * 2 + 0];
    const float sx = hwShiftAngs[b * 2 + 1];

    #pragma unroll
    for (int j = 0; j < 4; ++j) {
        const int tt = r + 64 * j;                 // frequency index (pre-shift)
        const int h  = (tt + D / 2) & (D - 1);     // fftshifted row
        const float ky = (float)(h - D / 2);
        const float2 z = Xf[tt];
        const float ph = -2.0f * (ky * sy + (float)x * sx) * (1.0f / (float)D);
        float ps, pc;
        sincospif(ph, &ps, &pc);
        const float ore = z.x * pc - z.y * ps;
        const float oim = z.x * ps + z.y * pc;
        const size_t o = (size_t)(b * D + h) * WR + x;
        const float cf = ctf[o];
        F4[o] = make_float4(cf * ore, cf * oim, cf * cf, 0.f);
    }
}

// ---------------------------------------------------------------------------
// Kernel 3: tiled GATHER.
// Round-2 change: branch-free fixed 4x4 candidate window per (particle,fold).
//   The bbox radii are L1 norms of rotation columns (<= sqrt3), so the true
//   integer window is at most 4 wide in each of ky,kx. We unroll it fully:
//   - weights via w = max(0,1-|dz|)*max(0,1-|dy|)*max(0,1-|dx|)  (the max(0,.)
//     subsumes every <1 test from the reference),
//   - fold membership ((rx<0)==(fi==1)) and index bounds fold into one select,
//   - F4 load is UNCONDITIONAL at a clamped address -> 16 independent loads
//     in flight per particle-fold (latency hidden by MLP, not branches),
//   - zero exec-mask divergence inside the window: each lane uses its own
//     ky0/kx0, no per-wave union walk.
// Round-1 keepers: 4x4x4 wave footprint (slab coherence), L1-norm radii,
//   per-row hoisted fold constants. rx stays bit-identical to the scatter ref.
// ---------------------------------------------------------------------------
#define TX 16
#define TY 4
#define TZ 4

__global__ void __launch_bounds__(256) gather_kernel(const float4* __restrict__ F4,
                                                     const float* __restrict__ rotMats,
                                                     float* __restrict__ out) {
    __shared__ float aR[B][12];
    __shared__ int   aBase[B];
    __shared__ int   na_s;

    const int t  = threadIdx.x;
    const int x0 = blockIdx.x * TX;
    const int y0 = blockIdx.y * TY;
    const int z0 = blockIdx.z * TZ;

    const float cx = (float)x0 + 7.5f;
    const float cy = (float)y0 + 1.5f - 128.f;
    const float cz = (float)z0 + 1.5f - 128.f;

    if (t < 64) {                       // wave 0: particle culling + compaction
        const float* R = rotMats + t * 9;
        const float R0 = R[0], R1 = R[1], R2 = R[2];
        const float R3 = R[3], R4 = R[4], R5 = R[5];
        const float R6 = R[6], R7 = R[7], R8 = R[8];
        const float qzc = R0 * cz + R3 * cy + R6 * cx;
        const float qyc = R1 * cz + R4 * cy + R7 * cx;
        const float qxc = R2 * cz + R5 * cy + R8 * cx;
        const float radz = fabsf(R0) + fabsf(R3) + fabsf(R6);   // ||col_z||_1
        const float rady = fabsf(R1) + fabsf(R4) + fabsf(R7);   // ||col_y||_1
        const float radx = fabsf(R2) + fabsf(R5) + fabsf(R8);   // ||col_x||_1
        const float mz = radz  + 1.5f * fabsf(R0) + 1.5f * fabsf(R3) + 7.5f * fabsf(R6);
        const float my = 130.f + 1.5f * fabsf(R1) + 1.5f * fabsf(R4) + 7.5f * fabsf(R7);
        const float mx = 130.f + 1.5f * fabsf(R2) + 1.5f * fabsf(R5) + 7.5f * fabsf(R8);
        const bool pass = (fabsf(qzc) < mz) & (fabsf(qyc) < my) & (fabsf(qxc) < mx);
        const unsigned long long m = __ballot(pass);
        if (t == 0) na_s = (int)__popcll(m);
        if (pass) {
            const int a = (int)__popcll(m & ((1ull << t) - 1ull));
            aR[a][0] = R0; aR[a][1] = R3; aR[a][2]  = R6;  aR[a][3]  = radz; // col z
            aR[a][4] = R1; aR[a][5] = R4; aR[a][6]  = R7;  aR[a][7]  = rady; // col y
            aR[a][8] = R2; aR[a][9] = R5; aR[a][10] = R8;  aR[a][11] = radx; // col x
            aBase[a] = t * D * WR;
        }
    }
    __syncthreads();

    // 4x4x4 subcube per wave; waves tile x in 4-wide chunks
    const int x = x0 + ((t >> 6) << 2) + (t & 3);
    const int y = y0 + ((t >> 2) & 3);
    const int z = z0 + ((t >> 4) & 3);
    if (x >= WR) return;               // only in the last x-tile; no barriers below

    const float vx = (float)x;
    const float vy = (float)(y - 128);
    const float vz = (float)(z - 128);

    float nre = 0.f, nim = 0.f, wv = 0.f, cv = 0.f;
    const int na = na_s;

    for (int a = 0; a < na; ++a) {
        const float* Rb = aR[a];
        const float qz = Rb[0] * vz + Rb[1] * vy + Rb[2] * vx;
        const float radz = Rb[3];
        if (fabsf(qz) >= radz) continue;
        const float R1 = Rb[4], R4 = Rb[5], R7 = Rb[6];
        const float rady = Rb[7];
        const float R2 = Rb[8], R5 = Rb[9], R8 = Rb[10];
        const float radx = Rb[11];
        const float qy = R1 * vz + R4 * vy + R7 * vx;
        const float qx = R2 * vz + R5 * vy + R8 * vx;
        const int base = aBase[a];

        #pragma unroll
        for (int fi = 0; fi < 2; ++fi) {
            const float fs = fi ? -1.f : 1.f;
            const float ty = fi ? -qy : qy;
            const float tx = fi ? -qx : qx;
            // cheap reject when the window misses the grid entirely
            if (ty + rady < -128.f || ty - rady > 127.f ||
                tx + radx < 0.f    || tx - radx > 128.f) continue;

            const int ky0 = max((int)ceilf(ty - rady), -D / 2);
            const int kx0 = max((int)ceilf(tx - radx), 0);
            const float sR1 = fs * R1, sR4 = fs * R4;
            const float sR2 = fs * R2, sR5 = fs * R5;

            #pragma unroll
            for (int i = 0; i < 4; ++i) {
                const int kyi = ky0 + i;
                const float kyf = (float)kyi;
                const float sxr = R7 * kyf;                 // rx partial (scatter-exact)
                const float bz  = fmaf(sR1, kyf, -vz);
                const float by  = fmaf(sR4, kyf, -vy);
                const bool yin  = (kyi <= D / 2 - 1);
                const int rowb  = base + (min(kyi, D / 2 - 1) + D / 2) * WR;
                #pragma unroll
                for (int j = 0; j < 4; ++j) {
                    const int kxi = kx0 + j;
                    const float kxf = (float)kxi;
                    const float rx  = fmaf(R8, kxf, sxr);   // matches scatter expr
                    const float dz_ = fmaf(sR2, kxf, bz);
                    const float dy_ = fmaf(sR5, kxf, by);
                    const float dx_ = fs * rx - vx;
                    float w = fmaxf(0.f, 1.f - fabsf(dz_)) *
                              fmaxf(0.f, 1.f - fabsf(dy_)) *
                              fmaxf(0.f, 1.f - fabsf(dx_));
                    const bool ok = (((rx < 0.f) == (fi == 1)) & yin & (kxi <= WR - 1));
                    w = ok ? w : 0.f;
                    const float4 v = F4[rowb + min(kxi, WR - 1)];
                    nre = fmaf(w, v.x, nre);
                    nim = fmaf(fi ? -w : w, v.y, nim);
                    wv += w;
                    cv  = fmaf(w, v.z, cv);
                }
            }
        }
    }

    const long idx = (long)z * (D * WR) + (long)y * WR + x;
    out[idx]          = nre;
    out[PL + idx]     = nim;
    out[2 * PL + idx] = wv;
    out[3 * PL + idx] = cv;
}

// ---------------------------------------------------------------------------
extern "C" void kernel_launch(void* const* d_in, const int* in_sizes, int n_in,
                              void* d_out, int out_size, void* d_ws, size_t ws_size,
                              hipStream_t stream) {
    const float* imgs    = (const float*)d_in[0];   // [B, D, D]
    const float* ctf     = (const float*)d_in[1];   // [B, D, WR]
    const float* rotMats = (const float*)d_in[2];   // [B, 3, 3]
    const float* hw      = (const float*)d_in[3];   // [B, 2]
    float* out = (float*)d_out;                     // [4, D, D, WR]

    float2* F1T = (float2*)d_ws;                                   // [B,WR,D] complex (16.9 MB)
    float4* F4  = (float4*)((char*)d_ws + (size_t)B * D * WR * 8); // [B,D,WR] float4 (33.8 MB)

    row_fft_kernel<<<B * D / 2 / 4, 256, 0, stream>>>(imgs, F1T);
    col_fft_kernel<<<B * WR / 4, 256, 0, stream>>>(F1T, ctf, hw, F4);

    dim3 grid((WR + TX - 1) / TX, D / TY, D / TZ);   // 9 x 64 x 64
    gather_kernel<<<grid, 256, 0, stream>>>(F4, rotMats, out);
}

// Round 3
// 356.158 us; speedup vs baseline: 1.5389x; 1.3463x over previous
//
#include <hip/hip_runtime.h>

#define D   256
#define WR  129          // D/2 + 1
#define B   64
static constexpr long PL = (long)D * D * WR;   // one output plane: 8,454,144 floats

// Padded F4 layout: [B][259][132] float4. 3 guard rows (h=256..258) and 3 guard
// cols (x=129..131) are zero (memset each launch); valid texels carry w=1.0 in
// .w so out-of-range taps contribute exactly nothing to all four accumulators.
#define F4H 259
#define F4W 132
static constexpr int F4PP = F4H * F4W;         // per-particle float4 count

// ===========================================================================
// Radix-2 Stockham FFT, 256-point, one wave per transform, 4 transforms per
// 256-thread block, LDS ping-pong. Twiddles: tw256[j] = exp(-2*pi*i*j/256).
// ===========================================================================

// ---------------------------------------------------------------------------
// Kernel 1: row rfft. Packs rows (2rp, 2rp+1) as one complex signal, FFTs,
// untangles to 129 bins, writes transposed F1T[b][k][y] (float2).
// ---------------------------------------------------------------------------
__global__ void __launch_bounds__(256) row_fft_kernel(const float* __restrict__ imgs,
                                                      float2* __restrict__ F1T) {
    __shared__ float2 Xs[4][D];
    __shared__ float2 Ys[4][D];
    __shared__ float2 tws[128];

    const int t = threadIdx.x;
    const int f = t >> 6;
    const int r = t & 63;
    const int blk = blockIdx.x;
    const int b   = blk >> 5;
    const int rp  = ((blk & 31) << 2) + f;

    if (t < 128) {
        float s, c;
        sincospif(-(float)t * (1.0f / 128.0f), &s, &c);
        tws[t] = make_float2(c, s);
    }

    {
        const float* r0 = imgs + ((size_t)(b * D + 2 * rp)) * D;
        const float* r1 = r0 + D;
        #pragma unroll
        for (int j = 0; j < 4; ++j) {
            const int n = r + 64 * j;
            Xs[f][n] = make_float2(r0[n], r1[n]);
        }
    }
    __syncthreads();

    float2* Xf = Xs[f];
    float2* Yf = Ys[f];
    #pragma unroll
    for (int st = 0; st < 8; ++st) {
        float2* src = (st & 1) ? Yf : Xf;
        float2* dst = (st & 1) ? Xf : Yf;
        const int sB = 1 << st;
        #pragma unroll
        for (int hh = 0; hh < 2; ++hh) {
            const int u  = r + 64 * hh;
            const int pm = u & ~(sB - 1);
            const float2 a  = src[u];
            const float2 bv = src[u + 128];
            const float2 w  = tws[pm];
            const float dx = a.x - bv.x, dy = a.y - bv.y;
            const int o = u + pm;
            dst[o]      = make_float2(a.x + bv.x, a.y + bv.y);
            dst[o + sB] = make_float2(dx * w.x - dy * w.y, dx * w.y + dy * w.x);
        }
        __syncthreads();
    }

    for (int k = r; k <= 128; k += 64) {
        const float2 zk = Xf[k];
        const float2 zm = Xf[(256 - k) & 255];
        const float4 o4 = make_float4(0.5f * (zk.x + zm.x), 0.5f * (zk.y - zm.y),
                                      0.5f * (zk.y + zm.y), -0.5f * (zk.x - zm.x));
        *(float4*)&F1T[((size_t)(b * WR + k)) * D + 2 * rp] = o4;
    }
}

// ---------------------------------------------------------------------------
// Kernel 2: column FFT over y for each (b,x), + fftshift + phase + CTF.
// Writes padded F4 [B][259][132] with .w = 1.0 validity marker.
// ---------------------------------------------------------------------------
__global__ void __launch_bounds__(256) col_fft_kernel(const float2* __restrict__ F1T,
                                                      const float* __restrict__ ctf,
                                                      const float* __restrict__ hwShiftAngs,
                                                      float4* __restrict__ F4) {
    __shared__ float2 Xs[4][D];
    __shared__ float2 Ys[4][D];
    __shared__ float2 tws[128];

    const int t = threadIdx.x;
    const int f = t >> 6;
    const int r = t & 63;
    const int c = blockIdx.x * 4 + f;   // b*129 + x
    const int b = c / WR;
    const int x = c - b * WR;

    if (t < 128) {
        float s, cc;
        sincospif(-(float)t * (1.0f / 128.0f), &s, &cc);
        tws[t] = make_float2(cc, s);
    }

    {
        const float2* src = F1T + (size_t)c * D;
        #pragma unroll
        for (int j = 0; j < 4; ++j) {
            const int n = r + 64 * j;
            Xs[f][n] = src[n];
        }
    }
    __syncthreads();

    float2* Xf = Xs[f];
    float2* Yf = Ys[f];
    #pragma unroll
    for (int st = 0; st < 8; ++st) {
        float2* src = (st & 1) ? Yf : Xf;
        float2* dst = (st & 1) ? Xf : Yf;
        const int sB = 1 << st;
        #pragma unroll
        for (int hh = 0; hh < 2; ++hh) {
            const int u  = r + 64 * hh;
            const int pm = u & ~(sB - 1);
            const float2 a  = src[u];
            const float2 bv = src[u + 128];
            const float2 w  = tws[pm];
            const float dx = a.x - bv.x, dy = a.y - bv.y;
            const int o = u + pm;
            dst[o]      = make_float2(a.x + bv.x, a.y + bv.y);
            dst[o + sB] = make_float2(dx * w.x - dy * w.y, dx * w.y + dy * w.x);
        }
        __syncthreads();
    }

    const float sy = hwShiftAngs[b * 2 + 0];
    const float sx = hwShiftAngs[b * 2 + 1];

    #pragma unroll
    for (int j = 0; j < 4; ++j) {
        const int tt = r + 64 * j;
        const int h  = (tt + D / 2) & (D - 1);
        const float ky = (float)(h - D / 2);
        const float2 z = Xf[tt];
        const float ph = -2.0f * (ky * sy + (float)x * sx) * (1.0f / (float)D);
        float ps, pc;
        sincospif(ph, &ps, &pc);
        const float ore = z.x * pc - z.y * ps;
        const float oim = z.x * ps + z.y * pc;
        const float cf = ctf[(size_t)(b * D + h) * WR + x];
        F4[(size_t)(b * F4H + h) * F4W + x] = make_float4(cf * ore, cf * oim, cf * cf, 1.0f);
    }
}

// ---------------------------------------------------------------------------
// Kernel 3: tiled GATHER.
// Round-3 changes:
//  (a) padded-F4 + validity-channel: all bounds checks / clamps vanish; OOB
//      taps load zeros (wv accumulates w*v.w).
//  (b) adaptive 3-vs-4 candidate window per particle axis (r<1.5 => interval
//      length 2r<3 => at most 3 integers). 4 template-unrolled variants,
//      wave-uniform dispatch.
//  (c) LDS store transpose: full 64B-contiguous row stores.
//  (d) center-out blockIdx.y/z remap: heaviest (origin-adjacent) blocks first.
// Kept: 4x4x4 wave footprint, L1-norm radii, scatter-exact rx expression.
// ---------------------------------------------------------------------------
#define TX 16
#define TY 4
#define TZ 4

__device__ __forceinline__ int cperm(int i) {   // 0,1,2,... -> 32,31,33,30,...
    const int half = (i + 1) >> 1;
    return (i & 1) ? 32 - half : 32 + half;
}

template<int NKY, int NKX>
__device__ __forceinline__ void accum_particle(
    const float4 c1, const float4 c2, const int base,
    const float vx, const float vy, const float vz,
    const float qy, const float qx,
    const float4* __restrict__ F4,
    float& nre, float& nim, float& wv, float& cv)
{
    const float R1 = c1.x, R4 = c1.y, R7 = c1.z, rady = c1.w;
    const float R2 = c2.x, R5 = c2.y, R8 = c2.z, radx = c2.w;

    #pragma unroll
    for (int fi = 0; fi < 2; ++fi) {
        const float fsgn = fi ? -1.f : 1.f;
        const float ty = fi ? -qy : qy;
        const float tx = fi ? -qx : qx;
        if (ty + rady < -128.f || ty - rady > 127.f ||
            tx + radx < 0.f    || tx - radx > 128.f) continue;

        const int ky0 = max((int)ceilf(ty - rady), -128);
        const int kx0 = max((int)ceilf(tx - radx), 0);
        const float kx0f = (float)kx0;

        #pragma unroll
        for (int i = 0; i < NKY; ++i) {
            const int kyi = ky0 + i;
            const float kyf = (float)kyi;
            const float sxr = R7 * kyf;                    // rx partial (scatter-exact)
            const float bz  = fmaf(fsgn * R1, kyf, -vz);
            const float by  = fmaf(fsgn * R4, kyf, -vy);
            const float dxb = fsgn * sxr - vx;
            const float4* rowp = F4 + (base + (kyi + 128) * F4W + kx0);
            #pragma unroll
            for (int j = 0; j < NKX; ++j) {
                const float kxf = kx0f + (float)j;
                const float rx  = fmaf(R8, kxf, sxr);      // matches scatter expr
                const float dz_ = fmaf(fsgn * R2, kxf, bz);
                const float dy_ = fmaf(fsgn * R5, kxf, by);
                const float dx_ = fmaf(fsgn * R8, kxf, dxb);
                float w = fmaxf(0.f, 1.f - fabsf(dz_)) *
                          fmaxf(0.f, 1.f - fabsf(dy_)) *
                          fmaxf(0.f, 1.f - fabsf(dx_));
                w = ((rx < 0.f) == (fi == 1)) ? w : 0.f;   // fold membership
                const float4 v = rowp[j];
                nre = fmaf(w, v.x, nre);
                nim = fmaf(fi ? -w : w, v.y, nim);
                wv  = fmaf(w, v.w, wv);                    // v.w = 1 valid, 0 pad
                cv  = fmaf(w, v.z, cv);
            }
        }
    }
}

__global__ void __launch_bounds__(256) gather_kernel(const float4* __restrict__ F4,
                                                     const float* __restrict__ rotMats,
                                                     float* __restrict__ out) {
    __shared__ __align__(16) float aR[B][12];
    __shared__ int   aBase[B];
    __shared__ int   aNk[B];
    __shared__ int   na_s;
    __shared__ float smv[4][256];

    const int t  = threadIdx.x;
    const int x0 = blockIdx.x * TX;
    const int y0 = cperm(blockIdx.y) * TY;
    const int z0 = cperm(blockIdx.z) * TZ;

    const float cx = (float)x0 + 7.5f;
    const float cy = (float)y0 + 1.5f - 128.f;
    const float cz = (float)z0 + 1.5f - 128.f;

    if (t < 64) {                       // wave 0: particle culling + compaction
        const float* R = rotMats + t * 9;
        const float R0 = R[0], R1 = R[1], R2 = R[2];
        const float R3 = R[3], R4 = R[4], R5 = R[5];
        const float R6 = R[6], R7 = R[7], R8 = R[8];
        const float qzc = R0 * cz + R3 * cy + R6 * cx;
        const float qyc = R1 * cz + R4 * cy + R7 * cx;
        const float qxc = R2 * cz + R5 * cy + R8 * cx;
        const float radz = fabsf(R0) + fabsf(R3) + fabsf(R6);   // ||col_z||_1
        const float rady = fabsf(R1) + fabsf(R4) + fabsf(R7);
        const float radx = fabsf(R2) + fabsf(R5) + fabsf(R8);
        const float mz = radz  + 1.5f * fabsf(R0) + 1.5f * fabsf(R3) + 7.5f * fabsf(R6);
        const float my = 130.f + 1.5f * fabsf(R1) + 1.5f * fabsf(R4) + 7.5f * fabsf(R7);
        const float mx = 130.f + 1.5f * fabsf(R2) + 1.5f * fabsf(R5) + 7.5f * fabsf(R8);
        const bool pass = (fabsf(qzc) < mz) & (fabsf(qyc) < my) & (fabsf(qxc) < mx);
        const unsigned long long m = __ballot(pass);
        if (t == 0) na_s = (int)__popcll(m);
        if (pass) {
            const int a = (int)__popcll(m & ((1ull << t) - 1ull));
            aR[a][0] = R0; aR[a][1] = R3; aR[a][2]  = R6;  aR[a][3]  = radz;
            aR[a][4] = R1; aR[a][5] = R4; aR[a][6]  = R7;  aR[a][7]  = rady;
            aR[a][8] = R2; aR[a][9] = R5; aR[a][10] = R8;  aR[a][11] = radx;
            aBase[a] = t * F4PP;
            aNk[a] = ((rady >= 1.5f) ? 2 : 0) | ((radx >= 1.5f) ? 1 : 0);
        }
    }
    __syncthreads();

    // 4x4x4 subcube per wave; waves tile x in 4-wide chunks
    const int x = x0 + ((t >> 6) << 2) + (t & 3);
    const int y = y0 + ((t >> 2) & 3);
    const int z = z0 + ((t >> 4) & 3);

    float nre = 0.f, nim = 0.f, wv = 0.f, cv = 0.f;

    if (x < WR) {                       // inactive lanes only in last x-tile
        const float vx = (float)x;
        const float vy = (float)(y - 128);
        const float vz = (float)(z - 128);
        const int na = na_s;

        for (int a = 0; a < na; ++a) {
            const float4 c0 = *(const float4*)&aR[a][0];
            const float qz = c0.x * vz + c0.y * vy + c0.z * vx;
            if (fabsf(qz) >= c0.w) continue;
            const float4 c1 = *(const float4*)&aR[a][4];
            const float4 c2 = *(const float4*)&aR[a][8];
            const float qy = c1.x * vz + c1.y * vy + c1.z * vx;
            const float qx = c2.x * vz + c2.y * vy + c2.z * vx;
            const int base = aBase[a];
            switch (aNk[a]) {           // wave-uniform (per-particle)
                case 0: accum_particle<3,3>(c1, c2, base, vx, vy, vz, qy, qx, F4, nre, nim, wv, cv); break;
                case 1: accum_particle<3,4>(c1, c2, base, vx, vy, vz, qy, qx, F4, nre, nim, wv, cv); break;
                case 2: accum_particle<4,3>(c1, c2, base, vx, vy, vz, qy, qx, F4, nre, nim, wv, cv); break;
                default: accum_particle<4,4>(c1, c2, base, vx, vy, vz, qy, qx, F4, nre, nim, wv, cv); break;
            }
        }
    }

    // ---- LDS store transpose: re-emit as 64B-contiguous rows ----
    __syncthreads();                    // aR reads done
    const int lin_c = (((t >> 4) & 3) << 6) | (((t >> 2) & 3) << 4) | (((t >> 6) & 3) << 2) | (t & 3);
    smv[0][lin_c] = nre;
    smv[1][lin_c] = nim;
    smv[2][lin_c] = wv;
    smv[3][lin_c] = cv;
    __syncthreads();

    const int xs = t & 15, ys = (t >> 4) & 3, zs = t >> 6;
    if (x0 + xs < WR) {
        const int lin_s = (zs << 6) | (ys << 4) | xs;
        const long idx = (long)(z0 + zs) * (D * WR) + (long)(y0 + ys) * WR + (x0 + xs);
        out[idx]          = smv[0][lin_s];
        out[PL + idx]     = smv[1][lin_s];
        out[2 * PL + idx] = smv[2][lin_s];
        out[3 * PL + idx] = smv[3][lin_s];
    }
}

// ---------------------------------------------------------------------------
extern "C" void kernel_launch(void* const* d_in, const int* in_sizes, int n_in,
                              void* d_out, int out_size, void* d_ws, size_t ws_size,
                              hipStream_t stream) {
    const float* imgs    = (const float*)d_in[0];   // [B, D, D]
    const float* ctf     = (const float*)d_in[1];   // [B, D, WR]
    const float* rotMats = (const float*)d_in[2];   // [B, 3, 3]
    const float* hw      = (const float*)d_in[3];   // [B, 2]
    float* out = (float*)d_out;                     // [4, D, D, WR]

    float2* F1T = (float2*)d_ws;                                   // [B,WR,D] complex (16.9 MB)
    const size_t f1t_bytes = (size_t)B * WR * D * sizeof(float2);
    float4* F4  = (float4*)((char*)d_ws + f1t_bytes);              // [B,259,132] float4 (35.0 MB)
    const size_t f4_bytes = (size_t)B * F4PP * sizeof(float4);

    hipMemsetAsync(F4, 0, f4_bytes, stream);        // zero guard rows/cols (and .w)

    row_fft_kernel<<<B * D / 2 / 4, 256, 0, stream>>>(imgs, F1T);
    col_fft_kernel<<<B * WR / 4, 256, 0, stream>>>(F1T, ctf, hw, F4);

    dim3 grid((WR + TX - 1) / TX, D / TY, D / TZ);   // 9 x 64 x 64
    gather_kernel<<<grid, 256, 0, stream>>>(F4, rotMats, out);
}

// Round 4
// 355.197 us; speedup vs baseline: 1.5431x; 1.0027x over previous
//
#include <hip/hip_runtime.h>

#define D   256
#define WR  129          // D/2 + 1
#define B   64
static constexpr long PL = (long)D * D * WR;   // one output plane: 8,454,144 floats

// Padded F4 layout: [B][259][132] float4. 3 guard rows (h=256..258) and 3 guard
// cols (x=129..131) are zero (memset each launch); valid texels carry w=1.0 in
// .w so out-of-range taps contribute exactly nothing to all four accumulators.
#define F4H 259
#define F4W 132
static constexpr int F4PP = F4H * F4W;         // per-particle float4 count

// ===========================================================================
// Radix-4 Stockham DIF FFT, 256-point, one wave per transform, 4 transforms
// per block. 4 stages, conflict-free LDS via per-generation bit-permutation
// layouts:
//   gen0 (input)        : identity     (loads stride-1; stage0 reads r+64k)
//   gen1 (stage0 out)   : L1 = bits{2..5}->{0..3}, {0,1}->{4,5}, {6,7} keep
//   gen2 (stage1 out)   : L2 = {0,1}->{0,1}, {4,5}->{2,3}, {2,3}->{4,5}, keep hi
//   gen3 (stage2 out)   : identity
//   gen4 (stage3 out)   : identity  (natural order result)
// Every stage reads logical {r, r+64, r+128, r+192}; the layout maps make all
// reads AND writes land 16 bank-pairs x 4 lanes (the free b64 pattern).
// Twiddles: Tw[j] = exp(-2*pi*i*j/256), j=0..63; stage t uses Tw[r & ~(4^t-1)];
// w2, w3 computed in-register from w1.
// ===========================================================================

__device__ __forceinline__ int L1map(int i) {
    return ((i >> 2) & 15) | ((i & 3) << 4) | (i & 0xC0);
}
__device__ __forceinline__ int L2map(int i) {
    return (i & 3) | (((i >> 4) & 3) << 2) | (((i >> 2) & 3) << 4) | (i & 0xC0);
}

__device__ __forceinline__ void r4bf(const float2 a, const float2 b, const float2 c, const float2 d,
                                     const float2 w1,
                                     float2& y0, float2& y1, float2& y2, float2& y3) {
    const float apcx = a.x + c.x, apcy = a.y + c.y;
    const float amcx = a.x - c.x, amcy = a.y - c.y;
    const float bpdx = b.x + d.x, bpdy = b.y + d.y;
    const float bmdx = b.x - d.x, bmdy = b.y - d.y;
    y0 = make_float2(apcx + bpdx, apcy + bpdy);
    const float t1x = amcx + bmdy, t1y = amcy - bmdx;   // (a-c) - j(b-d)
    const float t2x = apcx - bpdx, t2y = apcy - bpdy;
    const float t3x = amcx - bmdy, t3y = amcy + bmdx;   // (a-c) + j(b-d)
    const float w2x = w1.x * w1.x - w1.y * w1.y, w2y = 2.f * w1.x * w1.y;
    const float w3x = w2x * w1.x - w2y * w1.y,  w3y = w2x * w1.y + w2y * w1.x;
    y1 = make_float2(t1x * w1.x - t1y * w1.y, t1x * w1.y + t1y * w1.x);
    y2 = make_float2(t2x * w2x - t2y * w2y, t2x * w2y + t2y * w2x);
    y3 = make_float2(t3x * w3x - t3y * w3y, t3x * w3y + t3y * w3x);
}

// caller must __syncthreads() after filling Xf. Result: natural order in Xf.
__device__ __forceinline__ void fft256_r4(float2* __restrict__ Xf, float2* __restrict__ Yf,
                                          const float2* __restrict__ Tw, const int r) {
    float2 y0, y1, y2, y3;
    // stage 0: X(id) -> Y(L1), p = r, tw = Tw[r]
    r4bf(Xf[r], Xf[r + 64], Xf[r + 128], Xf[r + 192], Tw[r], y0, y1, y2, y3);
    {
        const int o = 4 * r;
        Yf[L1map(o)]     = y0; Yf[L1map(o + 1)] = y1;
        Yf[L1map(o + 2)] = y2; Yf[L1map(o + 3)] = y3;
    }
    __syncthreads();
    // stage 1: Y(L1) -> X(L2), p = r>>2, q = r&3, tw = Tw[r & ~3]
    r4bf(Yf[L1map(r)], Yf[L1map(r + 64)], Yf[L1map(r + 128)], Yf[L1map(r + 192)],
         Tw[r & ~3], y0, y1, y2, y3);
    {
        const int o = (r & 3) + 16 * (r >> 2);
        Xf[L2map(o)]      = y0; Xf[L2map(o + 4)]  = y1;
        Xf[L2map(o + 8)]  = y2; Xf[L2map(o + 12)] = y3;
    }
    __syncthreads();
    // stage 2: X(L2) -> Y(id), p = r>>4, q = r&15, tw = Tw[r & ~15]
    r4bf(Xf[L2map(r)], Xf[L2map(r + 64)], Xf[L2map(r + 128)], Xf[L2map(r + 192)],
         Tw[r & ~15], y0, y1, y2, y3);
    {
        const int o = (r & 15) + 64 * (r >> 4);
        Yf[o]      = y0; Yf[o + 16] = y1;
        Yf[o + 32] = y2; Yf[o + 48] = y3;
    }
    __syncthreads();
    // stage 3: Y(id) -> X(id), p = 0, twiddle-free
    {
        const float2 a = Yf[r], b = Yf[r + 64], c = Yf[r + 128], d = Yf[r + 192];
        const float apcx = a.x + c.x, apcy = a.y + c.y;
        const float amcx = a.x - c.x, amcy = a.y - c.y;
        const float bpdx = b.x + d.x, bpdy = b.y + d.y;
        const float bmdx = b.x - d.x, bmdy = b.y - d.y;
        Xf[r]       = make_float2(apcx + bpdx, apcy + bpdy);
        Xf[r + 64]  = make_float2(amcx + bmdy, amcy - bmdx);
        Xf[r + 128] = make_float2(apcx - bpdx, apcy - bpdy);
        Xf[r + 192] = make_float2(amcx - bmdy, amcy + bmdx);
    }
    __syncthreads();
}

// ---------------------------------------------------------------------------
// Kernel 1: row rfft. Packs rows (2rp, 2rp+1) as one complex signal, FFTs,
// untangles to 129 bins, writes transposed F1T[b][k][y] (float2).
// ---------------------------------------------------------------------------
__global__ void __launch_bounds__(256) row_fft_kernel(const float* __restrict__ imgs,
                                                      float2* __restrict__ F1T) {
    __shared__ float2 Xs[4][D];
    __shared__ float2 Ys[4][D];
    __shared__ float2 Tw[64];

    const int t = threadIdx.x;
    const int f = t >> 6;
    const int r = t & 63;
    const int blk = blockIdx.x;
    const int b   = blk >> 5;
    const int rp  = ((blk & 31) << 2) + f;

    if (t < 64) {
        float s, c;
        sincospif(-(float)t * (1.0f / 128.0f), &s, &c);
        Tw[t] = make_float2(c, s);
    }

    {
        const float* r0 = imgs + ((size_t)(b * D + 2 * rp)) * D;
        const float* r1 = r0 + D;
        #pragma unroll
        for (int j = 0; j < 4; ++j) {
            const int n = r + 64 * j;
            Xs[f][n] = make_float2(r0[n], r1[n]);
        }
    }
    __syncthreads();

    fft256_r4(Xs[f], Ys[f], Tw, r);

    // untangle real pair + transposed store: F1T[(b*129+k)*256 + {2rp,2rp+1}]
    float2* Xf = Xs[f];
    for (int k = r; k <= 128; k += 64) {
        const float2 zk = Xf[k];
        const float2 zm = Xf[(256 - k) & 255];
        const float4 o4 = make_float4(0.5f * (zk.x + zm.x), 0.5f * (zk.y - zm.y),
                                      0.5f * (zk.y + zm.y), -0.5f * (zk.x - zm.x));
        *(float4*)&F1T[((size_t)(b * WR + k)) * D + 2 * rp] = o4;
    }
}

// ---------------------------------------------------------------------------
// Kernel 2: column FFT over y for each (b,x), + fftshift + phase + CTF.
// Writes padded F4 [B][259][132] with .w = 1.0 validity marker.
// ---------------------------------------------------------------------------
__global__ void __launch_bounds__(256) col_fft_kernel(const float2* __restrict__ F1T,
                                                      const float* __restrict__ ctf,
                                                      const float* __restrict__ hwShiftAngs,
                                                      float4* __restrict__ F4) {
    __shared__ float2 Xs[4][D];
    __shared__ float2 Ys[4][D];
    __shared__ float2 Tw[64];

    const int t = threadIdx.x;
    const int f = t >> 6;
    const int r = t & 63;
    const int c = blockIdx.x * 4 + f;   // b*129 + x
    const int b = c / WR;
    const int x = c - b * WR;

    if (t < 64) {
        float s, cc;
        sincospif(-(float)t * (1.0f / 128.0f), &s, &cc);
        Tw[t] = make_float2(cc, s);
    }

    {
        const float2* src = F1T + (size_t)c * D;
        #pragma unroll
        for (int j = 0; j < 4; ++j) {
            const int n = r + 64 * j;
            Xs[f][n] = src[n];
        }
    }
    __syncthreads();

    fft256_r4(Xs[f], Ys[f], Tw, r);

    const float sy = hwShiftAngs[b * 2 + 0];
    const float sx = hwShiftAngs[b * 2 + 1];
    float2* Xf = Xs[f];

    #pragma unroll
    for (int j = 0; j < 4; ++j) {
        const int tt = r + 64 * j;
        const int h  = (tt + D / 2) & (D - 1);
        const float ky = (float)(h - D / 2);
        const float2 z = Xf[tt];
        const float ph = -2.0f * (ky * sy + (float)x * sx) * (1.0f / (float)D);
        float ps, pc;
        sincospif(ph, &ps, &pc);
        const float ore = z.x * pc - z.y * ps;
        const float oim = z.x * ps + z.y * pc;
        const float cf = ctf[(size_t)(b * D + h) * WR + x];
        F4[(size_t)(b * F4H + h) * F4W + x] = make_float4(cf * ore, cf * oim, cf * cf, 1.0f);
    }
}

// ---------------------------------------------------------------------------
// Kernel 3: tiled GATHER.
// Round-4 changes:
//  (a) per-WAVE particle culling: each wave culls the 64 particles against its
//      own 4x4x4 cube (mz = 2.5*radz vs ~6.7 for the block box) -> na halves,
//      listed particles hit more often. Per-wave LDS segments, ballot-compact.
//  (b) smv store-transpose swizzle idx = lin + 2*(lin>>4): write banks exactly
//      2 lanes/bank (free), reads <=3-way. Kills 3.5M conflict cycles.
// Kept from round 3: padded-F4 + validity channel (no bounds checks), adaptive
// 3-vs-4 window templates, center-out block remap, scatter-exact rx.
// ---------------------------------------------------------------------------
#define TX 16
#define TY 4
#define TZ 4

__device__ __forceinline__ int cperm(int i) {   // 0,1,2,... -> 32,31,33,30,...
    const int half = (i + 1) >> 1;
    return (i & 1) ? 32 - half : 32 + half;
}

template<int NKY, int NKX>
__device__ __forceinline__ void accum_particle(
    const float4 c1, const float4 c2, const int base,
    const float vx, const float vy, const float vz,
    const float qy, const float qx,
    const float4* __restrict__ F4,
    float& nre, float& nim, float& wv, float& cv)
{
    const float R1 = c1.x, R4 = c1.y, R7 = c1.z, rady = c1.w;
    const float R2 = c2.x, R5 = c2.y, R8 = c2.z, radx = c2.w;

    #pragma unroll
    for (int fi = 0; fi < 2; ++fi) {
        const float fsgn = fi ? -1.f : 1.f;
        const float ty = fi ? -qy : qy;
        const float tx = fi ? -qx : qx;
        if (ty + rady < -128.f || ty - rady > 127.f ||
            tx + radx < 0.f    || tx - radx > 128.f) continue;

        const int ky0 = max((int)ceilf(ty - rady), -128);
        const int kx0 = max((int)ceilf(tx - radx), 0);
        const float kx0f = (float)kx0;

        #pragma unroll
        for (int i = 0; i < NKY; ++i) {
            const int kyi = ky0 + i;
            const float kyf = (float)kyi;
            const float sxr = R7 * kyf;                    // rx partial (scatter-exact)
            const float bz  = fmaf(fsgn * R1, kyf, -vz);
            const float by  = fmaf(fsgn * R4, kyf, -vy);
            const float dxb = fsgn * sxr - vx;
            const float4* rowp = F4 + (base + (kyi + 128) * F4W + kx0);
            #pragma unroll
            for (int j = 0; j < NKX; ++j) {
                const float kxf = kx0f + (float)j;
                const float rx  = fmaf(R8, kxf, sxr);      // matches scatter expr
                const float dz_ = fmaf(fsgn * R2, kxf, bz);
                const float dy_ = fmaf(fsgn * R5, kxf, by);
                const float dx_ = fmaf(fsgn * R8, kxf, dxb);
                float w = fmaxf(0.f, 1.f - fabsf(dz_)) *
                          fmaxf(0.f, 1.f - fabsf(dy_)) *
                          fmaxf(0.f, 1.f - fabsf(dx_));
                w = ((rx < 0.f) == (fi == 1)) ? w : 0.f;   // fold membership
                const float4 v = rowp[j];
                nre = fmaf(w, v.x, nre);
                nim = fmaf(fi ? -w : w, v.y, nim);
                wv  = fmaf(w, v.w, wv);                    // v.w = 1 valid, 0 pad
                cv  = fmaf(w, v.z, cv);
            }
        }
    }
}

__global__ void __launch_bounds__(256) gather_kernel(const float4* __restrict__ F4,
                                                     const float* __restrict__ rotMats,
                                                     float* __restrict__ out) {
    __shared__ __align__(16) float4 aC[4][B][3];   // per-wave compacted particle data
    __shared__ int aMeta[4][B];                    // (particle_id<<2) | nk
    __shared__ float smv[4][288];                  // padded store-transpose buffer

    const int t = threadIdx.x;
    const int w = t >> 6;
    const int r = t & 63;
    const int x0 = blockIdx.x * TX;
    const int y0 = cperm(blockIdx.y) * TY;
    const int z0 = cperm(blockIdx.z) * TZ;

    // ---- per-wave cull: wave w's 4x4x4 cube center ----
    const float cx = (float)(x0 + 4 * w) + 1.5f;
    const float cy = (float)y0 + 1.5f - 128.f;
    const float cz = (float)z0 + 1.5f - 128.f;

    unsigned long long m;
    {
        const float* R = rotMats + r * 9;
        const float R0 = R[0], R1 = R[1], R2 = R[2];
        const float R3 = R[3], R4 = R[4], R5 = R[5];
        const float R6 = R[6], R7 = R[7], R8 = R[8];
        const float qzc = R0 * cz + R3 * cy + R6 * cx;
        const float qyc = R1 * cz + R4 * cy + R7 * cx;
        const float qxc = R2 * cz + R5 * cy + R8 * cx;
        const float radz = fabsf(R0) + fabsf(R3) + fabsf(R6);   // ||col_z||_1
        const float rady = fabsf(R1) + fabsf(R4) + fabsf(R7);
        const float radx = fabsf(R2) + fabsf(R5) + fabsf(R8);
        const float mz = 2.5f * radz;                 // radz + 1.5*radz (cube spread)
        const float my = 130.f + 1.5f * rady;
        const float mx = 130.f + 1.5f * radx;
        const bool pass = (fabsf(qzc) < mz) & (fabsf(qyc) < my) & (fabsf(qxc) < mx);
        m = __ballot(pass);
        if (pass) {
            const int a = (int)__popcll(m & ((1ull << r) - 1ull));
            aC[w][a][0] = make_float4(R0, R3, R6, radz);
            aC[w][a][1] = make_float4(R1, R4, R7, rady);
            aC[w][a][2] = make_float4(R2, R5, R8, radx);
            aMeta[w][a] = (r << 2) | ((rady >= 1.5f) ? 2 : 0) | ((radx >= 1.5f) ? 1 : 0);
        }
    }
    const int na = (int)__popcll(m);
    __syncthreads();   // conservative LDS write->read ordering

    // 4x4x4 subcube per wave; waves tile x in 4-wide chunks
    const int x = x0 + (w << 2) + (t & 3);
    const int y = y0 + ((t >> 2) & 3);
    const int z = z0 + ((t >> 4) & 3);

    float nre = 0.f, nim = 0.f, wv = 0.f, cv = 0.f;

    if (x < WR) {                       // inactive lanes only in last x-tile
        const float vx = (float)x;
        const float vy = (float)(y - 128);
        const float vz = (float)(z - 128);

        for (int a = 0; a < na; ++a) {
            const float4 c0 = aC[w][a][0];
            const float qz = c0.x * vz + c0.y * vy + c0.z * vx;
            if (fabsf(qz) >= c0.w) continue;
            const float4 c1 = aC[w][a][1];
            const float4 c2 = aC[w][a][2];
            const float qy = c1.x * vz + c1.y * vy + c1.z * vx;
            const float qx = c2.x * vz + c2.y * vy + c2.z * vx;
            const int meta = aMeta[w][a];
            const int base = (meta >> 2) * F4PP;
            switch (meta & 3) {         // wave-uniform (per-particle)
                case 0: accum_particle<3,3>(c1, c2, base, vx, vy, vz, qy, qx, F4, nre, nim, wv, cv); break;
                case 1: accum_particle<3,4>(c1, c2, base, vx, vy, vz, qy, qx, F4, nre, nim, wv, cv); break;
                case 2: accum_particle<4,3>(c1, c2, base, vx, vy, vz, qy, qx, F4, nre, nim, wv, cv); break;
                default: accum_particle<4,4>(c1, c2, base, vx, vy, vz, qy, qx, F4, nre, nim, wv, cv); break;
            }
        }
    }

    // ---- LDS store transpose (swizzled): re-emit as 64B-contiguous rows ----
    const int lin_c = (((t >> 4) & 3) << 6) | (((t >> 2) & 3) << 4) | ((t >> 6) << 2) | (t & 3);
    const int sc = lin_c + 2 * (lin_c >> 4);
    smv[0][sc] = nre;
    smv[1][sc] = nim;
    smv[2][sc] = wv;
    smv[3][sc] = cv;
    __syncthreads();

    const int xs = t & 15, ys = (t >> 4) & 3, zs = t >> 6;
    if (x0 + xs < WR) {
        const int lin_s = (zs << 6) | (ys << 4) | xs;
        const int ss = lin_s + 2 * (lin_s >> 4);
        const long idx = (long)(z0 + zs) * (D * WR) + (long)(y0 + ys) * WR + (x0 + xs);
        out[idx]          = smv[0][ss];
        out[PL + idx]     = smv[1][ss];
        out[2 * PL + idx] = smv[2][ss];
        out[3 * PL + idx] = smv[3][ss];
    }
}

// ---------------------------------------------------------------------------
extern "C" void kernel_launch(void* const* d_in, const int* in_sizes, int n_in,
                              void* d_out, int out_size, void* d_ws, size_t ws_size,
                              hipStream_t stream) {
    const float* imgs    = (const float*)d_in[0];   // [B, D, D]
    const float* ctf     = (const float*)d_in[1];   // [B, D, WR]
    const float* rotMats = (const float*)d_in[2];   // [B, 3, 3]
    const float* hw      = (const float*)d_in[3];   // [B, 2]
    float* out = (float*)d_out;                     // [4, D, D, WR]

    float2* F1T = (float2*)d_ws;                                   // [B,WR,D] complex (16.9 MB)
    const size_t f1t_bytes = (size_t)B * WR * D * sizeof(float2);
    float4* F4  = (float4*)((char*)d_ws + f1t_bytes);              // [B,259,132] float4 (35.0 MB)
    const size_t f4_bytes = (size_t)B * F4PP * sizeof(float4);

    hipMemsetAsync(F4, 0, f4_bytes, stream);        // zero guard rows/cols (and .w)

    row_fft_kernel<<<B * D / 2 / 4, 256, 0, stream>>>(imgs, F1T);
    col_fft_kernel<<<B * WR / 4, 256, 0, stream>>>(F1T, ctf, hw, F4);

    dim3 grid((WR + TX - 1) / TX, D / TY, D / TZ);   // 9 x 64 x 64
    gather_kernel<<<grid, 256, 0, stream>>>(F4, rotMats, out);
}

// Round 5
// 333.527 us; speedup vs baseline: 1.6433x; 1.0650x over previous
//
#include <hip/hip_runtime.h>

#define D   256
#define WR  129          // D/2 + 1
#define B   64
static constexpr long PL = (long)D * D * WR;   // one output plane: 8,454,144 floats

// Padded F4 layout: [B][259][132] float4. 3 guard rows (h=256..258) and 3 guard
// cols (x=129..131) are zero (written by col_fft's g=32 blocks; no memset);
// valid texels carry w=1.0 in .w so OOB taps contribute exactly nothing.
#define F4H 259
#define F4W 132
static constexpr int F4PP = F4H * F4W;         // per-particle float4 count

// ===========================================================================
// Radix-4 Stockham DIF FFT, 256-point, one wave per transform, 4 transforms
// per block (verified round-4 version, unchanged).
// ===========================================================================

__device__ __forceinline__ int L1map(int i) {
    return ((i >> 2) & 15) | ((i & 3) << 4) | (i & 0xC0);
}
__device__ __forceinline__ int L2map(int i) {
    return (i & 3) | (((i >> 4) & 3) << 2) | (((i >> 2) & 3) << 4) | (i & 0xC0);
}

__device__ __forceinline__ void r4bf(const float2 a, const float2 b, const float2 c, const float2 d,
                                     const float2 w1,
                                     float2& y0, float2& y1, float2& y2, float2& y3) {
    const float apcx = a.x + c.x, apcy = a.y + c.y;
    const float amcx = a.x - c.x, amcy = a.y - c.y;
    const float bpdx = b.x + d.x, bpdy = b.y + d.y;
    const float bmdx = b.x - d.x, bmdy = b.y - d.y;
    y0 = make_float2(apcx + bpdx, apcy + bpdy);
    const float t1x = amcx + bmdy, t1y = amcy - bmdx;   // (a-c) - j(b-d)
    const float t2x = apcx - bpdx, t2y = apcy - bpdy;
    const float t3x = amcx - bmdy, t3y = amcy + bmdx;   // (a-c) + j(b-d)
    const float w2x = w1.x * w1.x - w1.y * w1.y, w2y = 2.f * w1.x * w1.y;
    const float w3x = w2x * w1.x - w2y * w1.y,  w3y = w2x * w1.y + w2y * w1.x;
    y1 = make_float2(t1x * w1.x - t1y * w1.y, t1x * w1.y + t1y * w1.x);
    y2 = make_float2(t2x * w2x - t2y * w2y, t2x * w2y + t2y * w2x);
    y3 = make_float2(t3x * w3x - t3y * w3y, t3x * w3y + t3y * w3x);
}

// caller must __syncthreads() after filling Xf. Result: natural order in Xf.
__device__ __forceinline__ void fft256_r4(float2* __restrict__ Xf, float2* __restrict__ Yf,
                                          const float2* __restrict__ Tw, const int r) {
    float2 y0, y1, y2, y3;
    r4bf(Xf[r], Xf[r + 64], Xf[r + 128], Xf[r + 192], Tw[r], y0, y1, y2, y3);
    {
        const int o = 4 * r;
        Yf[L1map(o)]     = y0; Yf[L1map(o + 1)] = y1;
        Yf[L1map(o + 2)] = y2; Yf[L1map(o + 3)] = y3;
    }
    __syncthreads();
    r4bf(Yf[L1map(r)], Yf[L1map(r + 64)], Yf[L1map(r + 128)], Yf[L1map(r + 192)],
         Tw[r & ~3], y0, y1, y2, y3);
    {
        const int o = (r & 3) + 16 * (r >> 2);
        Xf[L2map(o)]      = y0; Xf[L2map(o + 4)]  = y1;
        Xf[L2map(o + 8)]  = y2; Xf[L2map(o + 12)] = y3;
    }
    __syncthreads();
    r4bf(Xf[L2map(r)], Xf[L2map(r + 64)], Xf[L2map(r + 128)], Xf[L2map(r + 192)],
         Tw[r & ~15], y0, y1, y2, y3);
    {
        const int o = (r & 15) + 64 * (r >> 4);
        Yf[o]      = y0; Yf[o + 16] = y1;
        Yf[o + 32] = y2; Yf[o + 48] = y3;
    }
    __syncthreads();
    {
        const float2 a = Yf[r], b = Yf[r + 64], c = Yf[r + 128], d = Yf[r + 192];
        const float apcx = a.x + c.x, apcy = a.y + c.y;
        const float amcx = a.x - c.x, amcy = a.y - c.y;
        const float bpdx = b.x + d.x, bpdy = b.y + d.y;
        const float bmdx = b.x - d.x, bmdy = b.y - d.y;
        Xf[r]       = make_float2(apcx + bpdx, apcy + bpdy);
        Xf[r + 64]  = make_float2(amcx + bmdy, amcy - bmdx);
        Xf[r + 128] = make_float2(apcx - bpdx, apcy - bpdy);
        Xf[r + 192] = make_float2(amcx - bmdy, amcy + bmdx);
    }
    __syncthreads();
}

__device__ __forceinline__ float4 untangle(const float2 zk, const float2 zm) {
    // Fe = 0.5(zk + conj(zm)); Fo = -0.5i(zk - conj(zm))
    return make_float4(0.5f * (zk.x + zm.x), 0.5f * (zk.y - zm.y),
                       0.5f * (zk.y + zm.y), -0.5f * (zk.x - zm.x));
}

// ---------------------------------------------------------------------------
// Kernel 1: row rfft. Round-5: untangled results staged in aliased LDS
// U[129][4] (k-major, wave-minor), then cooperatively stored so 4 consecutive
// lanes fill each 64B line of F1T completely (fully dense wave stores).
// ---------------------------------------------------------------------------
__global__ void __launch_bounds__(256) row_fft_kernel(const float* __restrict__ imgs,
                                                      float2* __restrict__ F1T) {
    __shared__ __align__(16) float smem[4096];   // 16 KB: X[4][256] | Y[4][256]
    __shared__ float2 Tw[64];

    const int t = threadIdx.x;
    const int f = t >> 6;
    const int r = t & 63;
    const int blk = blockIdx.x;
    const int b   = blk >> 5;
    const int Y0  = (blk & 31) << 3;             // first of 8 consecutive rows

    float2* Xf = (float2*)smem + f * 256;
    float2* Yf = (float2*)smem + 1024 + f * 256;
    float4* U  = (float4*)smem;                  // [129][4], aliases X/Y

    if (t < 64) {
        float s, c;
        sincospif(-(float)t * (1.0f / 128.0f), &s, &c);
        Tw[t] = make_float2(c, s);
    }

    {
        const float* r0 = imgs + ((size_t)(b * D + Y0 + 2 * f)) * D;
        const float* r1 = r0 + D;
        #pragma unroll
        for (int j = 0; j < 4; ++j) {
            const int n = r + 64 * j;
            Xf[n] = make_float2(r0[n], r1[n]);
        }
    }
    __syncthreads();

    fft256_r4(Xf, Yf, Tw, r);

    // register-stage the untangle reads (U aliases X/Y)
    const float2 zk0 = Xf[r],       zm0 = Xf[(256 - r) & 255];
    const float2 zk1 = Xf[r + 64],  zm1 = Xf[192 - r];
    float2 zk2 = make_float2(0.f, 0.f);
    if (r == 0) zk2 = Xf[128];
    __syncthreads();

    U[r * 4 + f]        = untangle(zk0, zm0);
    U[(r + 64) * 4 + f] = untangle(zk1, zm1);
    if (r == 0) U[128 * 4 + f] = untangle(zk2, zk2);
    __syncthreads();

    // cooperative coalesced store: e = k*4 + ff; 4 lanes fill one 64B line
    for (int e = t; e < 516; e += 256) {
        const int k = e >> 2, ff = e & 3;
        *(float4*)&F1T[((size_t)(b * WR + k)) * D + Y0 + 2 * ff] = U[e];
    }
}

// ---------------------------------------------------------------------------
// Kernel 2: column FFT + fftshift + phase + CTF. Round-5: grid regrouped as
// (g, b) with x = 4g + f so the 4 waves' outputs are 4 consecutive x columns;
// results staged in aliased LDS V[256][4] and stored cooperatively (dense 64B
// lines). g=32 block also writes guard cols x=129..131 (zeros via the same
// path) and guard rows h=256..258 -> memset eliminated entirely.
// ---------------------------------------------------------------------------
__global__ void __launch_bounds__(256) col_fft_kernel(const float2* __restrict__ F1T,
                                                      const float* __restrict__ ctf,
                                                      const float* __restrict__ hwShiftAngs,
                                                      float4* __restrict__ F4) {
    __shared__ __align__(16) float smem[4096];   // 16 KB: X[4][256] | Y[4][256]
    __shared__ float2 Tw[64];

    const int t = threadIdx.x;
    const int f = t >> 6;
    const int r = t & 63;
    const int g = blockIdx.x;            // x-group: x = 4g + f
    const int b = blockIdx.y;
    const int x = 4 * g + f;
    const bool xvalid = (x < WR);

    float2* Xf = (float2*)smem + f * 256;
    float2* Yf = (float2*)smem + 1024 + f * 256;
    float4* V  = (float4*)smem;                  // [256][4], aliases X/Y

    if (t < 64) {
        float s, cc;
        sincospif(-(float)t * (1.0f / 128.0f), &s, &cc);
        Tw[t] = make_float2(cc, s);
    }

    // prefetch ctf (scattered 4B reads; latency hidden under the FFT)
    float cfv[4];
    #pragma unroll
    for (int j = 0; j < 4; ++j) {
        const int tt = r + 64 * j;
        const int h  = (tt + D / 2) & (D - 1);
        cfv[j] = xvalid ? ctf[(size_t)(b * D + h) * WR + x] : 0.f;
    }

    {
        const float2* src = F1T + (size_t)(b * WR + (xvalid ? x : 0)) * D;
        #pragma unroll
        for (int j = 0; j < 4; ++j) {
            const int n = r + 64 * j;
            Xf[n] = xvalid ? src[n] : make_float2(0.f, 0.f);
        }
    }
    __syncthreads();

    fft256_r4(Xf, Yf, Tw, r);

    const float sy = hwShiftAngs[b * 2 + 0];
    const float sx = hwShiftAngs[b * 2 + 1];
    const float vw = xvalid ? 1.0f : 0.0f;

    // compute fully in registers (V aliases X/Y), then barrier, then stage
    float4 o4[4];
    int    hh[4];
    #pragma unroll
    for (int j = 0; j < 4; ++j) {
        const int tt = r + 64 * j;
        const int h  = (tt + D / 2) & (D - 1);
        hh[j] = h;
        const float ky = (float)(h - D / 2);
        const float2 z = Xf[tt];
        const float ph = -2.0f * (ky * sy + (float)x * sx) * (1.0f / (float)D);
        float ps, pc;
        sincospif(ph, &ps, &pc);
        const float ore = z.x * pc - z.y * ps;
        const float oim = z.x * ps + z.y * pc;
        const float cf = cfv[j];
        o4[j] = make_float4(cf * ore, cf * oim, cf * cf, vw);
    }
    __syncthreads();

    #pragma unroll
    for (int j = 0; j < 4; ++j) V[hh[j] * 4 + f] = o4[j];
    __syncthreads();

    // cooperative coalesced store: e = h*4 + fx; 4 lanes fill one 64B line
    const size_t base = (size_t)b * F4PP + 4 * g;
    #pragma unroll
    for (int p = 0; p < 4; ++p) {
        const int e = t + 256 * p;
        const int h = e >> 2, fx = e & 3;
        F4[base + (size_t)h * F4W + fx] = V[e];
    }

    if (g == 32) {   // guard rows h=256..258 (3*132 float4 per particle)
        const size_t gb = (size_t)b * F4PP + 256 * F4W;
        for (int e = t; e < 3 * F4W; e += 256)
            F4[gb + e] = make_float4(0.f, 0.f, 0.f, 0.f);
    }
}

// ---------------------------------------------------------------------------
// Kernel 3: tiled GATHER — unchanged from round 4.
// ---------------------------------------------------------------------------
#define TX 16
#define TY 4
#define TZ 4

__device__ __forceinline__ int cperm(int i) {   // 0,1,2,... -> 32,31,33,30,...
    const int half = (i + 1) >> 1;
    return (i & 1) ? 32 - half : 32 + half;
}

template<int NKY, int NKX>
__device__ __forceinline__ void accum_particle(
    const float4 c1, const float4 c2, const int base,
    const float vx, const float vy, const float vz,
    const float qy, const float qx,
    const float4* __restrict__ F4,
    float& nre, float& nim, float& wv, float& cv)
{
    const float R1 = c1.x, R4 = c1.y, R7 = c1.z, rady = c1.w;
    const float R2 = c2.x, R5 = c2.y, R8 = c2.z, radx = c2.w;

    #pragma unroll
    for (int fi = 0; fi < 2; ++fi) {
        const float fsgn = fi ? -1.f : 1.f;
        const float ty = fi ? -qy : qy;
        const float tx = fi ? -qx : qx;
        if (ty + rady < -128.f || ty - rady > 127.f ||
            tx + radx < 0.f    || tx - radx > 128.f) continue;

        const int ky0 = max((int)ceilf(ty - rady), -128);
        const int kx0 = max((int)ceilf(tx - radx), 0);
        const float kx0f = (float)kx0;

        #pragma unroll
        for (int i = 0; i < NKY; ++i) {
            const int kyi = ky0 + i;
            const float kyf = (float)kyi;
            const float sxr = R7 * kyf;                    // rx partial (scatter-exact)
            const float bz  = fmaf(fsgn * R1, kyf, -vz);
            const float by  = fmaf(fsgn * R4, kyf, -vy);
            const float dxb = fsgn * sxr - vx;
            const float4* rowp = F4 + (base + (kyi + 128) * F4W + kx0);
            #pragma unroll
            for (int j = 0; j < NKX; ++j) {
                const float kxf = kx0f + (float)j;
                const float rx  = fmaf(R8, kxf, sxr);      // matches scatter expr
                const float dz_ = fmaf(fsgn * R2, kxf, bz);
                const float dy_ = fmaf(fsgn * R5, kxf, by);
                const float dx_ = fmaf(fsgn * R8, kxf, dxb);
                float w = fmaxf(0.f, 1.f - fabsf(dz_)) *
                          fmaxf(0.f, 1.f - fabsf(dy_)) *
                          fmaxf(0.f, 1.f - fabsf(dx_));
                w = ((rx < 0.f) == (fi == 1)) ? w : 0.f;   // fold membership
                const float4 v = rowp[j];
                nre = fmaf(w, v.x, nre);
                nim = fmaf(fi ? -w : w, v.y, nim);
                wv  = fmaf(w, v.w, wv);                    // v.w = 1 valid, 0 pad
                cv  = fmaf(w, v.z, cv);
            }
        }
    }
}

__global__ void __launch_bounds__(256) gather_kernel(const float4* __restrict__ F4,
                                                     const float* __restrict__ rotMats,
                                                     float* __restrict__ out) {
    __shared__ __align__(16) float4 aC[4][B][3];   // per-wave compacted particle data
    __shared__ int aMeta[4][B];                    // (particle_id<<2) | nk
    __shared__ float smv[4][288];                  // padded store-transpose buffer

    const int t = threadIdx.x;
    const int w = t >> 6;
    const int r = t & 63;
    const int x0 = blockIdx.x * TX;
    const int y0 = cperm(blockIdx.y) * TY;
    const int z0 = cperm(blockIdx.z) * TZ;

    // ---- per-wave cull: wave w's 4x4x4 cube center ----
    const float cx = (float)(x0 + 4 * w) + 1.5f;
    const float cy = (float)y0 + 1.5f - 128.f;
    const float cz = (float)z0 + 1.5f - 128.f;

    unsigned long long m;
    {
        const float* R = rotMats + r * 9;
        const float R0 = R[0], R1 = R[1], R2 = R[2];
        const float R3 = R[3], R4 = R[4], R5 = R[5];
        const float R6 = R[6], R7 = R[7], R8 = R[8];
        const float qzc = R0 * cz + R3 * cy + R6 * cx;
        const float qyc = R1 * cz + R4 * cy + R7 * cx;
        const float qxc = R2 * cz + R5 * cy + R8 * cx;
        const float radz = fabsf(R0) + fabsf(R3) + fabsf(R6);   // ||col_z||_1
        const float rady = fabsf(R1) + fabsf(R4) + fabsf(R7);
        const float radx = fabsf(R2) + fabsf(R5) + fabsf(R8);
        const float mz = 2.5f * radz;                 // radz + 1.5*radz (cube spread)
        const float my = 130.f + 1.5f * rady;
        const float mx = 130.f + 1.5f * radx;
        const bool pass = (fabsf(qzc) < mz) & (fabsf(qyc) < my) & (fabsf(qxc) < mx);
        m = __ballot(pass);
        if (pass) {
            const int a = (int)__popcll(m & ((1ull << r) - 1ull));
            aC[w][a][0] = make_float4(R0, R3, R6, radz);
            aC[w][a][1] = make_float4(R1, R4, R7, rady);
            aC[w][a][2] = make_float4(R2, R5, R8, radx);
            aMeta[w][a] = (r << 2) | ((rady >= 1.5f) ? 2 : 0) | ((radx >= 1.5f) ? 1 : 0);
        }
    }
    const int na = (int)__popcll(m);
    __syncthreads();   // conservative LDS write->read ordering

    // 4x4x4 subcube per wave; waves tile x in 4-wide chunks
    const int x = x0 + (w << 2) + (t & 3);
    const int y = y0 + ((t >> 2) & 3);
    const int z = z0 + ((t >> 4) & 3);

    float nre = 0.f, nim = 0.f, wv = 0.f, cv = 0.f;

    if (x < WR) {                       // inactive lanes only in last x-tile
        const float vx = (float)x;
        const float vy = (float)(y - 128);
        const float vz = (float)(z - 128);

        for (int a = 0; a < na; ++a) {
            const float4 c0 = aC[w][a][0];
            const float qz = c0.x * vz + c0.y * vy + c0.z * vx;
            if (fabsf(qz) >= c0.w) continue;
            const float4 c1 = aC[w][a][1];
            const float4 c2 = aC[w][a][2];
            const float qy = c1.x * vz + c1.y * vy + c1.z * vx;
            const float qx = c2.x * vz + c2.y * vy + c2.z * vx;
            const int meta = aMeta[w][a];
            const int base = (meta >> 2) * F4PP;
            switch (meta & 3) {         // wave-uniform (per-particle)
                case 0: accum_particle<3,3>(c1, c2, base, vx, vy, vz, qy, qx, F4, nre, nim, wv, cv); break;
                case 1: accum_particle<3,4>(c1, c2, base, vx, vy, vz, qy, qx, F4, nre, nim, wv, cv); break;
                case 2: accum_particle<4,3>(c1, c2, base, vx, vy, vz, qy, qx, F4, nre, nim, wv, cv); break;
                default: accum_particle<4,4>(c1, c2, base, vx, vy, vz, qy, qx, F4, nre, nim, wv, cv); break;
            }
        }
    }

    // ---- LDS store transpose (swizzled): re-emit as 64B-contiguous rows ----
    const int lin_c = (((t >> 4) & 3) << 6) | (((t >> 2) & 3) << 4) | ((t >> 6) << 2) | (t & 3);
    const int sc = lin_c + 2 * (lin_c >> 4);
    smv[0][sc] = nre;
    smv[1][sc] = nim;
    smv[2][sc] = wv;
    smv[3][sc] = cv;
    __syncthreads();

    const int xs = t & 15, ys = (t >> 4) & 3, zs = t >> 6;
    if (x0 + xs < WR) {
        const int lin_s = (zs << 6) | (ys << 4) | xs;
        const int ss = lin_s + 2 * (lin_s >> 4);
        const long idx = (long)(z0 + zs) * (D * WR) + (long)(y0 + ys) * WR + (x0 + xs);
        out[idx]          = smv[0][ss];
        out[PL + idx]     = smv[1][ss];
        out[2 * PL + idx] = smv[2][ss];
        out[3 * PL + idx] = smv[3][ss];
    }
}

// ---------------------------------------------------------------------------
extern "C" void kernel_launch(void* const* d_in, const int* in_sizes, int n_in,
                              void* d_out, int out_size, void* d_ws, size_t ws_size,
                              hipStream_t stream) {
    const float* imgs    = (const float*)d_in[0];   // [B, D, D]
    const float* ctf     = (const float*)d_in[1];   // [B, D, WR]
    const float* rotMats = (const float*)d_in[2];   // [B, 3, 3]
    const float* hw      = (const float*)d_in[3];   // [B, 2]
    float* out = (float*)d_out;                     // [4, D, D, WR]

    float2* F1T = (float2*)d_ws;                                   // [B,WR,D] complex (16.9 MB)
    const size_t f1t_bytes = (size_t)B * WR * D * sizeof(float2);
    float4* F4  = (float4*)((char*)d_ws + f1t_bytes);              // [B,259,132] float4 (35.0 MB)

    row_fft_kernel<<<B * D / 2 / 4, 256, 0, stream>>>(imgs, F1T);
    col_fft_kernel<<<dim3(33, B), 256, 0, stream>>>(F1T, ctf, hw, F4);

    dim3 grid((WR + TX - 1) / TX, D / TY, D / TZ);   // 9 x 64 x 64
    gather_kernel<<<grid, 256, 0, stream>>>(F4, rotMats, out);
}